// Round 1
// baseline (145.980 us; speedup 1.0000x reference)
//
#include <hip/hip_runtime.h>

// Problem constants: d=64, nq=1024, nk=2048, h=64
// ws layout (floats): qp[1024][64] @0, kp[2048][64] @65536,
//                     p[1024][2048] @196608, l[1024] @2293760

// ---------------- K1: projections ----------------
// qp[n][h] = b1[h] + sum_d W1[h][d]     * query[d][n]
// kp[m][h] =         sum_d W1[h][64+d]  * key[d][m]
// Block = 256 threads computes a 64(row) x 4(h) tile; lane=row for coalesced
// src reads + s_load-able uniform W1 rows; LDS transpose for coalesced writes.
__global__ __launch_bounds__(256) void k1_proj(
    const float* __restrict__ q, const float* __restrict__ k,
    const float* __restrict__ W1, const float* __restrict__ b1,
    float* __restrict__ qp, float* __restrict__ kp)
{
  __shared__ float tile[256];
  const int t = threadIdx.x;
  const int b = blockIdx.x;
  if (b < 256) {                      // qp: 16 n-tiles x 16 h-tiles
    const int nb = (b & 15) << 6;
    const int hb = (b >> 4) << 2;
    const int n = nb + (t & 63);
    const int h = hb + (t >> 6);      // wave-uniform
    const float* wr = W1 + h * 128;
    float acc = b1[h];
#pragma unroll
    for (int d = 0; d < 64; ++d) acc = fmaf(wr[d], q[(d << 10) + n], acc);
    tile[((t & 63) << 2) + (t >> 6)] = acc;
    __syncthreads();
    qp[((nb + (t >> 2)) << 6) + hb + (t & 3)] = tile[t];
  } else {                            // kp: 32 m-tiles x 16 h-tiles
    const int b2 = b - 256;
    const int mb = (b2 & 31) << 6;
    const int hb = (b2 >> 5) << 2;
    const int m = mb + (t & 63);
    const int h = hb + (t >> 6);
    const float* wr = W1 + h * 128 + 64;
    float acc = 0.f;
#pragma unroll
    for (int d = 0; d < 64; ++d) acc = fmaf(wr[d], k[(d << 11) + m], acc);
    tile[((t & 63) << 2) + (t >> 6)] = acc;
    __syncthreads();
    kp[((mb + (t >> 2)) << 6) + hb + (t & 3)] = tile[t];
  }
}

// ---------------- K2: scores + exp + partial softmax denominator ----------------
// Grid 512 = 128 q-tiles (8 q each) x 4 k-splits (512 k each).
// Thread: 2 q rows in VGPRs (128 regs), 1 k lane; kp chunk (256 x 64) staged in
// 64 KB LDS with XOR swizzle (conflict-minimal b128 row reads, no padding).
__global__ __launch_bounds__(256, 2) void k2_scores(
    const float* __restrict__ qp, const float* __restrict__ kp,
    const float* __restrict__ W2, const float* __restrict__ b2p,
    float* __restrict__ scores, float* __restrict__ pbuf,
    float* __restrict__ lbuf)
{
  __shared__ float4 lds4[4096];       // 256 rows x 16 float4 = 64 KB exactly
  const int t = threadIdx.x;
  const int lane = t & 63;
  const int wave = t >> 6;
  const int qt = blockIdx.x >> 2;
  const int ks = blockIdx.x & 3;
  const int q0 = (qt << 3) + (wave << 1);

  const float4* qp4 = (const float4*)(qp + (q0 << 6));
  float4 qa[16], qb[16];
#pragma unroll
  for (int i = 0; i < 16; ++i) { qa[i] = qp4[i]; qb[i] = qp4[16 + i]; }

  const float4* w24 = (const float4*)W2;
  const float b2v = b2p[0];
  const float4* kp4 = (const float4*)kp;
  const int sw = lane & 15;           // (s*64+lane)&15 == lane&15

  float lacc0 = 0.f, lacc1 = 0.f;

  for (int c = 0; c < 2; ++c) {
    const int kb = (ks << 9) + (c << 8);
    if (c) __syncthreads();
#pragma unroll
    for (int i = 0; i < 16; ++i) {    // stage 256 kp rows, coalesced
      const int idx = (i << 8) + t;
      const int row = idx >> 4;
      const int c4 = idx & 15;
      lds4[(row << 4) + (c4 ^ (row & 15))] = kp4[((kb + row) << 4) + c4];
    }
    __syncthreads();
    for (int s = 0; s < 4; ++s) {
      const int kl = (s << 6) + lane;
      float4 A0 = {0.f,0.f,0.f,0.f}, A1 = {0.f,0.f,0.f,0.f};
#pragma unroll
      for (int h4 = 0; h4 < 16; ++h4) {
        const float4 kf = lds4[(kl << 4) + (h4 ^ sw)];
        const float4 wv = w24[h4];    // uniform -> s_load
        A0.x = fmaf(wv.x, fmaxf(qa[h4].x + kf.x, 0.f), A0.x);
        A0.y = fmaf(wv.y, fmaxf(qa[h4].y + kf.y, 0.f), A0.y);
        A0.z = fmaf(wv.z, fmaxf(qa[h4].z + kf.z, 0.f), A0.z);
        A0.w = fmaf(wv.w, fmaxf(qa[h4].w + kf.w, 0.f), A0.w);
        A1.x = fmaf(wv.x, fmaxf(qb[h4].x + kf.x, 0.f), A1.x);
        A1.y = fmaf(wv.y, fmaxf(qb[h4].y + kf.y, 0.f), A1.y);
        A1.z = fmaf(wv.z, fmaxf(qb[h4].z + kf.z, 0.f), A1.z);
        A1.w = fmaf(wv.w, fmaxf(qb[h4].w + kf.w, 0.f), A1.w);
      }
      const float s0 = A0.x + A0.y + A0.z + A0.w + b2v;
      const float s1 = A1.x + A1.y + A1.z + A1.w + b2v;
      const int kg = kb + kl;
      scores[(q0 << 11) + kg] = s0;
      scores[((q0 + 1) << 11) + kg] = s1;
      const float e0 = __expf(s0);
      const float e1 = __expf(s1);
      pbuf[(q0 << 11) + kg] = e0;
      pbuf[((q0 + 1) << 11) + kg] = e1;
      lacc0 += e0; lacc1 += e1;
    }
  }
#pragma unroll
  for (int off = 32; off > 0; off >>= 1) {
    lacc0 += __shfl_xor(lacc0, off);
    lacc1 += __shfl_xor(lacc1, off);
  }
  if (lane == 0) {
    atomicAdd(&lbuf[q0], lacc0);
    atomicAdd(&lbuf[q0 + 1], lacc1);
  }
}

// ---------------- K3: out[d][n] = (sum_m p[n][m] * v[d][m]) / l[n] ----------------
// Grid 256 blocks x 4 n each; waves split m into quarters (cross-wave LDS reduce).
// V chunks (64d x 64m) staged per-wave (no barriers needed) with SW prefetch;
// p rows are wave-uniform-address broadcast loads.
__global__ __launch_bounds__(256, 2) void k3_pv(
    const float* __restrict__ pbuf, const float* __restrict__ v,
    const float* __restrict__ lbuf, float* __restrict__ out)
{
  __shared__ float lds[16384];        // 4 waves x (64d x 64m) = 64 KB
  float4* lds4 = (float4*)lds;
  const int t = threadIdx.x;
  const int lane = t & 63;            // = d
  const int wave = t >> 6;
  const int nq0 = blockIdx.x << 2;
  const float4* v4 = (const float4*)v;
  const float4* p4 = (const float4*)pbuf;
  const int wb4 = wave << 10;
  const int dr = lane >> 4;
  const int c4s = lane & 15;
  const int mc4 = wave << 7;          // wave m-offset in float4 units

  float4 sreg[16];
#pragma unroll
  for (int r = 0; r < 16; ++r)
    sreg[r] = v4[(((r << 2) + dr) << 9) + mc4 + c4s];

  float a0 = 0.f, a1 = 0.f, a2 = 0.f, a3 = 0.f;
  for (int ch = 0; ch < 8; ++ch) {
#pragma unroll
    for (int r = 0; r < 16; ++r) {    // LDS write of current chunk
      const int d = (r << 2) + dr;
      lds4[wb4 + (d << 4) + (c4s ^ (d & 15))] = sreg[r];
    }
    if (ch < 7) {                     // prefetch next chunk during compute
      const int nmc4 = mc4 + ((ch + 1) << 4);
#pragma unroll
      for (int r = 0; r < 16; ++r)
        sreg[r] = v4[(((r << 2) + dr) << 9) + nmc4 + c4s];
    }
    const int pg = mc4 + (ch << 4);
#pragma unroll
    for (int m4 = 0; m4 < 16; ++m4) {
      const float4 vf = lds4[wb4 + (lane << 4) + (m4 ^ c4s)];
      const float4 pf0 = p4[((nq0 + 0) << 9) + pg + m4];
      const float4 pf1 = p4[((nq0 + 1) << 9) + pg + m4];
      const float4 pf2 = p4[((nq0 + 2) << 9) + pg + m4];
      const float4 pf3 = p4[((nq0 + 3) << 9) + pg + m4];
      a0 = fmaf(vf.x, pf0.x, a0); a0 = fmaf(vf.y, pf0.y, a0);
      a0 = fmaf(vf.z, pf0.z, a0); a0 = fmaf(vf.w, pf0.w, a0);
      a1 = fmaf(vf.x, pf1.x, a1); a1 = fmaf(vf.y, pf1.y, a1);
      a1 = fmaf(vf.z, pf1.z, a1); a1 = fmaf(vf.w, pf1.w, a1);
      a2 = fmaf(vf.x, pf2.x, a2); a2 = fmaf(vf.y, pf2.y, a2);
      a2 = fmaf(vf.z, pf2.z, a2); a2 = fmaf(vf.w, pf2.w, a2);
      a3 = fmaf(vf.x, pf3.x, a3); a3 = fmaf(vf.y, pf3.y, a3);
      a3 = fmaf(vf.z, pf3.z, a3); a3 = fmaf(vf.w, pf3.w, a3);
    }
  }
  __syncthreads();
  lds[(wave << 8) + lane] = a0;
  lds[(wave << 8) + 64 + lane] = a1;
  lds[(wave << 8) + 128 + lane] = a2;
  lds[(wave << 8) + 192 + lane] = a3;
  __syncthreads();
  const int qi = t & 3;
  const int d = t >> 2;
  const float sum = lds[(qi << 6) + d] + lds[256 + (qi << 6) + d] +
                    lds[512 + (qi << 6) + d] + lds[768 + (qi << 6) + d];
  out[(d << 10) + nq0 + qi] = sum / lbuf[nq0 + qi];
}

extern "C" void kernel_launch(void* const* d_in, const int* in_sizes, int n_in,
                              void* d_out, int out_size, void* d_ws, size_t ws_size,
                              hipStream_t stream) {
  const float* query = (const float*)d_in[0];
  const float* key   = (const float*)d_in[1];
  const float* value = (const float*)d_in[2];
  const float* W1    = (const float*)d_in[3];
  const float* b1    = (const float*)d_in[4];
  const float* W2    = (const float*)d_in[5];
  const float* b2    = (const float*)d_in[6];

  float* out    = (float*)d_out;       // (1,64,1024)
  float* scores = out + 65536;         // (1,1024,2048)

  float* ws = (float*)d_ws;
  float* qp = ws;                      // 1024*64
  float* kp = ws + 65536;              // 2048*64
  float* pb = ws + 196608;             // 1024*2048 (exp(scores))
  float* lb = ws + 2293760;            // 1024 softmax denominators

  hipMemsetAsync(lb, 0, 1024 * sizeof(float), stream);
  k1_proj<<<768, 256, 0, stream>>>(query, key, W1, b1, qp, kp);
  k2_scores<<<512, 256, 0, stream>>>(qp, kp, W2, b2, scores, pb, lb);
  k3_pv<<<256, 256, 0, stream>>>(pb, value, lb, out);
}

// Round 2
// 110.936 us; speedup vs baseline: 1.3159x; 1.3159x over previous
//
#include <hip/hip_runtime.h>

// Problem constants: d=64, nq=1024, nk=2048, h=64
// ws layout (floats): qp[1024][64] @0, kp[2048][64] @65536,
//                     p[1024][2048] @196608, l[1024] @2293760

// ---------------- K1: projections ----------------
__global__ __launch_bounds__(256) void k1_proj(
    const float* __restrict__ q, const float* __restrict__ k,
    const float* __restrict__ W1, const float* __restrict__ b1,
    float* __restrict__ qp, float* __restrict__ kp)
{
  __shared__ float tile[256];
  const int t = threadIdx.x;
  const int b = blockIdx.x;
  if (b < 256) {                      // qp: 16 n-tiles x 16 h-tiles
    const int nb = (b & 15) << 6;
    const int hb = (b >> 4) << 2;
    const int n = nb + (t & 63);
    const int h = hb + (t >> 6);      // wave-uniform
    const float* wr = W1 + h * 128;
    float acc = b1[h];
#pragma unroll
    for (int d = 0; d < 64; ++d) acc = fmaf(wr[d], q[(d << 10) + n], acc);
    tile[((t & 63) << 2) + (t >> 6)] = acc;
    __syncthreads();
    qp[((nb + (t >> 2)) << 6) + hb + (t & 3)] = tile[t];
  } else {                            // kp: 32 m-tiles x 16 h-tiles
    const int b2 = b - 256;
    const int mb = (b2 & 31) << 6;
    const int hb = (b2 >> 5) << 2;
    const int m = mb + (t & 63);
    const int h = hb + (t >> 6);
    const float* wr = W1 + h * 128 + 64;
    float acc = 0.f;
#pragma unroll
    for (int d = 0; d < 64; ++d) acc = fmaf(wr[d], k[(d << 11) + m], acc);
    tile[((t & 63) << 2) + (t >> 6)] = acc;
    __syncthreads();
    kp[((mb + (t >> 2)) << 6) + hb + (t & 3)] = tile[t];
  }
}

// ---------------- K2: scores + exp + partial softmax denominator ----------------
// (unchanged this round — isolating the k3 fix)
__global__ __launch_bounds__(256, 2) void k2_scores(
    const float* __restrict__ qp, const float* __restrict__ kp,
    const float* __restrict__ W2, const float* __restrict__ b2p,
    float* __restrict__ scores, float* __restrict__ pbuf,
    float* __restrict__ lbuf)
{
  __shared__ float4 lds4[4096];       // 256 rows x 16 float4 = 64 KB exactly
  const int t = threadIdx.x;
  const int lane = t & 63;
  const int wave = t >> 6;
  const int qt = blockIdx.x >> 2;
  const int ks = blockIdx.x & 3;
  const int q0 = (qt << 3) + (wave << 1);

  const float4* qp4 = (const float4*)(qp + (q0 << 6));
  float4 qa[16], qb[16];
#pragma unroll
  for (int i = 0; i < 16; ++i) { qa[i] = qp4[i]; qb[i] = qp4[16 + i]; }

  const float4* w24 = (const float4*)W2;
  const float b2v = b2p[0];
  const float4* kp4 = (const float4*)kp;
  const int sw = lane & 15;

  float lacc0 = 0.f, lacc1 = 0.f;

  for (int c = 0; c < 2; ++c) {
    const int kb = (ks << 9) + (c << 8);
    if (c) __syncthreads();
#pragma unroll
    for (int i = 0; i < 16; ++i) {    // stage 256 kp rows, coalesced
      const int idx = (i << 8) + t;
      const int row = idx >> 4;
      const int c4 = idx & 15;
      lds4[(row << 4) + (c4 ^ (row & 15))] = kp4[((kb + row) << 4) + c4];
    }
    __syncthreads();
    for (int s = 0; s < 4; ++s) {
      const int kl = (s << 6) + lane;
      float4 A0 = {0.f,0.f,0.f,0.f}, A1 = {0.f,0.f,0.f,0.f};
#pragma unroll
      for (int h4 = 0; h4 < 16; ++h4) {
        const float4 kf = lds4[(kl << 4) + (h4 ^ sw)];
        const float4 wv = w24[h4];
        A0.x = fmaf(wv.x, fmaxf(qa[h4].x + kf.x, 0.f), A0.x);
        A0.y = fmaf(wv.y, fmaxf(qa[h4].y + kf.y, 0.f), A0.y);
        A0.z = fmaf(wv.z, fmaxf(qa[h4].z + kf.z, 0.f), A0.z);
        A0.w = fmaf(wv.w, fmaxf(qa[h4].w + kf.w, 0.f), A0.w);
        A1.x = fmaf(wv.x, fmaxf(qb[h4].x + kf.x, 0.f), A1.x);
        A1.y = fmaf(wv.y, fmaxf(qb[h4].y + kf.y, 0.f), A1.y);
        A1.z = fmaf(wv.z, fmaxf(qb[h4].z + kf.z, 0.f), A1.z);
        A1.w = fmaf(wv.w, fmaxf(qb[h4].w + kf.w, 0.f), A1.w);
      }
      const float s0 = A0.x + A0.y + A0.z + A0.w + b2v;
      const float s1 = A1.x + A1.y + A1.z + A1.w + b2v;
      const int kg = kb + kl;
      scores[(q0 << 11) + kg] = s0;
      scores[((q0 + 1) << 11) + kg] = s1;
      const float e0 = __expf(s0);
      const float e1 = __expf(s1);
      pbuf[(q0 << 11) + kg] = e0;
      pbuf[((q0 + 1) << 11) + kg] = e1;
      lacc0 += e0; lacc1 += e1;
    }
  }
#pragma unroll
  for (int off = 32; off > 0; off >>= 1) {
    lacc0 += __shfl_xor(lacc0, off);
    lacc1 += __shfl_xor(lacc1, off);
  }
  if (lane == 0) {
    atomicAdd(&lbuf[q0], lacc0);
    atomicAdd(&lbuf[q0 + 1], lacc1);
  }
}

// ---------------- K3: split-k tiled GEMM. out[d][n] = sum_m p[n][m]*V[d][m] / l[n] ----
// Grid 256 = 16 n-tiles(64n) x 16 m-splits(128m). Block 256 thr, per-thread 2n x 8d.
// LDS: pS 64n x 32f4 (XOR swizzle) + vtS 128m x 16f4 transposed-V (XOR swizzle) = 64 KB.
// Per m-step: 4 ds_read_b128 feed 64 fma -> VALU-bound. Epilogue: scale 1/l, atomicAdd.
__global__ __launch_bounds__(256, 2) void k3_pv(
    const float* __restrict__ pbuf, const float* __restrict__ v,
    const float* __restrict__ lbuf, float* __restrict__ out)
{
  __shared__ float4 pS4[2048];        // 64 rows x 32 float4, col ^= (n&31)
  __shared__ float vtS[8192];         // 128 rows x 64 floats, f4-col ^= (m&15)
  float4* vtS4w = (float4*)vtS;
  const float4* vtS4 = (const float4*)vtS;
  const int t = threadIdx.x;
  const int nt = blockIdx.x >> 4;
  const int ms = blockIdx.x & 15;
  const int n0b = nt << 6;
  const int mc4 = ms << 5;            // m-chunk base in float4 units

  const float4* p4 = (const float4*)pbuf;
  const float4* v4 = (const float4*)v;
#pragma unroll
  for (int i = 0; i < 8; ++i) {       // stage p tile: 64 n x 32 f4, coalesced
    const int idx = (i << 8) + t;
    const int n = idx >> 5, c = idx & 31;
    pS4[(n << 5) + (c ^ (n & 31))] = p4[((n0b + n) << 9) + mc4 + c];
  }
#pragma unroll
  for (int i = 0; i < 8; ++i) {       // stage V chunk transposed: vtS[m][d]
    const int idx = (i << 8) + t;
    const int d = idx >> 5, c = idx & 31;
    const float4 val = v4[(d << 9) + mc4 + c];
    const int m0 = c << 2;
    const int dc = d >> 2, dl = d & 3;
    vtS[((m0 + 0) << 6) + ((dc ^ ((m0 + 0) & 15)) << 2) + dl] = val.x;
    vtS[((m0 + 1) << 6) + ((dc ^ ((m0 + 1) & 15)) << 2) + dl] = val.y;
    vtS[((m0 + 2) << 6) + ((dc ^ ((m0 + 2) & 15)) << 2) + dl] = val.z;
    vtS[((m0 + 3) << 6) + ((dc ^ ((m0 + 3) & 15)) << 2) + dl] = val.w;
  }
  __syncthreads();

  const int tn = t >> 3;              // 32 n-groups x 2n
  const int td = t & 7;               // 8 d-groups x 8d
  const int td2 = td << 1;
  const int n0l = tn << 1, n1l = n0l + 1;
  const int sw0 = n0l & 31, sw1 = n1l & 31;

  float4 acc00 = {0,0,0,0}, acc01 = {0,0,0,0};
  float4 acc10 = {0,0,0,0}, acc11 = {0,0,0,0};

#define PV_STEP(AC) {                                          \
    const int swm = m & 15;                                    \
    const float4 b0 = vtS4[(m << 4) + (td2 ^ swm)];            \
    const float4 b1 = vtS4[(m << 4) + ((td2 + 1) ^ swm)];      \
    acc00.x = fmaf(a0.AC, b0.x, acc00.x);                      \
    acc00.y = fmaf(a0.AC, b0.y, acc00.y);                      \
    acc00.z = fmaf(a0.AC, b0.z, acc00.z);                      \
    acc00.w = fmaf(a0.AC, b0.w, acc00.w);                      \
    acc01.x = fmaf(a0.AC, b1.x, acc01.x);                      \
    acc01.y = fmaf(a0.AC, b1.y, acc01.y);                      \
    acc01.z = fmaf(a0.AC, b1.z, acc01.z);                      \
    acc01.w = fmaf(a0.AC, b1.w, acc01.w);                      \
    acc10.x = fmaf(a1.AC, b0.x, acc10.x);                      \
    acc10.y = fmaf(a1.AC, b0.y, acc10.y);                      \
    acc10.z = fmaf(a1.AC, b0.z, acc10.z);                      \
    acc10.w = fmaf(a1.AC, b0.w, acc10.w);                      \
    acc11.x = fmaf(a1.AC, b1.x, acc11.x);                      \
    acc11.y = fmaf(a1.AC, b1.y, acc11.y);                      \
    acc11.z = fmaf(a1.AC, b1.z, acc11.z);                      \
    acc11.w = fmaf(a1.AC, b1.w, acc11.w);                      \
    ++m; }

#pragma unroll 8
  for (int m4 = 0; m4 < 32; ++m4) {
    const float4 a0 = pS4[(n0l << 5) + (m4 ^ sw0)];
    const float4 a1 = pS4[(n1l << 5) + (m4 ^ sw1)];
    int m = m4 << 2;
    PV_STEP(x) PV_STEP(y) PV_STEP(z) PV_STEP(w)
  }
#undef PV_STEP

  const int n0 = n0b + n0l;
  const float i0 = 1.0f / lbuf[n0];
  const float i1 = 1.0f / lbuf[n0 + 1];
  const int dbase = td << 3;
  atomicAdd(&out[((dbase + 0) << 10) + n0], acc00.x * i0);
  atomicAdd(&out[((dbase + 1) << 10) + n0], acc00.y * i0);
  atomicAdd(&out[((dbase + 2) << 10) + n0], acc00.z * i0);
  atomicAdd(&out[((dbase + 3) << 10) + n0], acc00.w * i0);
  atomicAdd(&out[((dbase + 4) << 10) + n0], acc01.x * i0);
  atomicAdd(&out[((dbase + 5) << 10) + n0], acc01.y * i0);
  atomicAdd(&out[((dbase + 6) << 10) + n0], acc01.z * i0);
  atomicAdd(&out[((dbase + 7) << 10) + n0], acc01.w * i0);
  atomicAdd(&out[((dbase + 0) << 10) + n0 + 1], acc10.x * i1);
  atomicAdd(&out[((dbase + 1) << 10) + n0 + 1], acc10.y * i1);
  atomicAdd(&out[((dbase + 2) << 10) + n0 + 1], acc10.z * i1);
  atomicAdd(&out[((dbase + 3) << 10) + n0 + 1], acc10.w * i1);
  atomicAdd(&out[((dbase + 4) << 10) + n0 + 1], acc11.x * i1);
  atomicAdd(&out[((dbase + 5) << 10) + n0 + 1], acc11.y * i1);
  atomicAdd(&out[((dbase + 6) << 10) + n0 + 1], acc11.z * i1);
  atomicAdd(&out[((dbase + 7) << 10) + n0 + 1], acc11.w * i1);
}

extern "C" void kernel_launch(void* const* d_in, const int* in_sizes, int n_in,
                              void* d_out, int out_size, void* d_ws, size_t ws_size,
                              hipStream_t stream) {
  const float* query = (const float*)d_in[0];
  const float* key   = (const float*)d_in[1];
  const float* value = (const float*)d_in[2];
  const float* W1    = (const float*)d_in[3];
  const float* b1    = (const float*)d_in[4];
  const float* W2    = (const float*)d_in[5];
  const float* b2    = (const float*)d_in[6];

  float* out    = (float*)d_out;       // (1,64,1024)
  float* scores = out + 65536;         // (1,1024,2048)

  float* ws = (float*)d_ws;
  float* qp = ws;                      // 1024*64
  float* kp = ws + 65536;              // 2048*64
  float* pb = ws + 196608;             // 1024*2048 (exp(scores))
  float* lb = ws + 2293760;            // 1024 softmax denominators

  hipMemsetAsync(lb, 0, 1024 * sizeof(float), stream);
  hipMemsetAsync(out, 0, 65536 * sizeof(float), stream);   // k3 accumulates atomically
  k1_proj<<<768, 256, 0, stream>>>(query, key, W1, b1, qp, kp);
  k2_scores<<<512, 256, 0, stream>>>(qp, kp, W2, b2, scores, pb, lb);
  k3_pv<<<256, 256, 0, stream>>>(pb, value, lb, out);
}

// Round 4
// 103.266 us; speedup vs baseline: 1.4136x; 1.0743x over previous
//
#include <hip/hip_runtime.h>

// Problem constants: d=64, nq=1024, nk=2048, h=64
// ws layout (floats): qp[1024][64] @0, kp[2048][64] @65536,
//   lpart[4][1024] @196608, part[32][1024][64] @200704  (n-major partials)
// scores lives in d_out (out[65536] then scores[1024*2048]); k2 writes it,
// k3 re-reads it and applies exp during LDS staging (pbuf eliminated).

// ---------------- K1: projections ----------------
__global__ __launch_bounds__(256) void k1_proj(
    const float* __restrict__ q, const float* __restrict__ k,
    const float* __restrict__ W1, const float* __restrict__ b1,
    float* __restrict__ qp, float* __restrict__ kp)
{
  __shared__ float tile[256];
  const int t = threadIdx.x;
  const int b = blockIdx.x;
  if (b < 256) {                      // qp: 16 n-tiles x 16 h-tiles
    const int nb = (b & 15) << 6;
    const int hb = (b >> 4) << 2;
    const int n = nb + (t & 63);
    const int h = hb + (t >> 6);      // wave-uniform
    const float* wr = W1 + h * 128;
    float acc = b1[h];
#pragma unroll
    for (int d = 0; d < 64; ++d) acc = fmaf(wr[d], q[(d << 10) + n], acc);
    tile[((t & 63) << 2) + (t >> 6)] = acc;
    __syncthreads();
    qp[((nb + (t >> 2)) << 6) + hb + (t & 3)] = tile[t];
  } else {                            // kp: 32 m-tiles x 16 h-tiles
    const int b2 = b - 256;
    const int mb = (b2 & 31) << 6;
    const int hb = (b2 >> 5) << 2;
    const int m = mb + (t & 63);
    const int h = hb + (t >> 6);
    const float* wr = W1 + h * 128 + 64;
    float acc = 0.f;
#pragma unroll
    for (int d = 0; d < 64; ++d) acc = fmaf(wr[d], k[(d << 11) + m], acc);
    tile[((t & 63) << 2) + (t >> 6)] = acc;
    __syncthreads();
    kp[((mb + (t >> 2)) << 6) + hb + (t & 3)] = tile[t];
  }
}

// ---------------- K2: scores + per-split softmax denominator partials ----------
__global__ __launch_bounds__(256, 2) void k2_scores(
    const float* __restrict__ qp, const float* __restrict__ kp,
    const float* __restrict__ W2, const float* __restrict__ b2p,
    float* __restrict__ scores, float* __restrict__ lpart)
{
  __shared__ float4 lds4[4096];       // 256 rows x 16 float4 = 64 KB
  const int t = threadIdx.x;
  const int lane = t & 63;
  const int wave = t >> 6;
  const int qt = blockIdx.x >> 2;
  const int ks = blockIdx.x & 3;
  const int q0 = (qt << 3) + (wave << 1);

  const float4* qp4 = (const float4*)(qp + (q0 << 6));
  float4 qa[16], qb[16];
#pragma unroll
  for (int i = 0; i < 16; ++i) { qa[i] = qp4[i]; qb[i] = qp4[16 + i]; }

  const float4* w24 = (const float4*)W2;
  const float b2v = b2p[0];
  const float4* kp4 = (const float4*)kp;
  const int sw = lane & 15;

  float lacc0 = 0.f, lacc1 = 0.f;

  for (int c = 0; c < 2; ++c) {
    const int kb = (ks << 9) + (c << 8);
    if (c) __syncthreads();
#pragma unroll
    for (int i = 0; i < 16; ++i) {    // stage 256 kp rows, coalesced
      const int idx = (i << 8) + t;
      const int row = idx >> 4;
      const int c4 = idx & 15;
      lds4[(row << 4) + (c4 ^ (row & 15))] = kp4[((kb + row) << 4) + c4];
    }
    __syncthreads();
    for (int s = 0; s < 4; ++s) {
      const int kl = (s << 6) + lane;
      float4 A0 = {0.f,0.f,0.f,0.f}, A1 = {0.f,0.f,0.f,0.f};
#pragma unroll
      for (int h4 = 0; h4 < 16; ++h4) {
        const float4 kf = lds4[(kl << 4) + (h4 ^ sw)];
        const float4 wv = w24[h4];
        A0.x = fmaf(wv.x, fmaxf(qa[h4].x + kf.x, 0.f), A0.x);
        A0.y = fmaf(wv.y, fmaxf(qa[h4].y + kf.y, 0.f), A0.y);
        A0.z = fmaf(wv.z, fmaxf(qa[h4].z + kf.z, 0.f), A0.z);
        A0.w = fmaf(wv.w, fmaxf(qa[h4].w + kf.w, 0.f), A0.w);
        A1.x = fmaf(wv.x, fmaxf(qb[h4].x + kf.x, 0.f), A1.x);
        A1.y = fmaf(wv.y, fmaxf(qb[h4].y + kf.y, 0.f), A1.y);
        A1.z = fmaf(wv.z, fmaxf(qb[h4].z + kf.z, 0.f), A1.z);
        A1.w = fmaf(wv.w, fmaxf(qb[h4].w + kf.w, 0.f), A1.w);
      }
      const float s0 = A0.x + A0.y + A0.z + A0.w + b2v;
      const float s1 = A1.x + A1.y + A1.z + A1.w + b2v;
      const int kg = kb + kl;
      scores[(q0 << 11) + kg] = s0;
      scores[((q0 + 1) << 11) + kg] = s1;
      lacc0 += __expf(s0);
      lacc1 += __expf(s1);
    }
  }
#pragma unroll
  for (int off = 32; off > 0; off >>= 1) {
    lacc0 += __shfl_xor(lacc0, off);
    lacc1 += __shfl_xor(lacc1, off);
  }
  if (lane == 0) {                    // unique (ks, q0) per wave: plain store
    lpart[(ks << 10) + q0] = lacc0;
    lpart[(ks << 10) + q0 + 1] = lacc1;
  }
}

// ---------------- K3: partial PV. part[ms][n][d] = sum_{m in split} p*V ------
// Grid 512 = 16 n-tiles(64n) x 32 m-splits(64m). Block 256, per-thread 2n x 8d.
// LDS 32 KB -> 2 blocks/CU, 2 waves/EU. exp applied during p staging.
// vtS col-swizzle: f4-col' = (d>>2) ^ ((m>>2)&15) -> transpose writes <=2-way,
// compute reads conflict-free within lane beats. No atomics anywhere.
__global__ __launch_bounds__(256, 2) void k3_pv(
    const float* __restrict__ scores, const float* __restrict__ v,
    float* __restrict__ part)
{
  __shared__ float4 pS4[1024];        // 64n x 16f4 row-major (exp(scores))
  __shared__ float4 vtS4[1024];       // 64m x 16f4 transposed V, swizzled
  float* vtSf = (float*)vtS4;
  const int t = threadIdx.x;
  const int nt = blockIdx.x >> 5;
  const int ms = blockIdx.x & 31;
  const int n0b = nt << 6;
  const int mc4 = ms << 4;

  const float4* s4 = (const float4*)scores;
  const float4* v4 = (const float4*)v;
#pragma unroll
  for (int i = 0; i < 4; ++i) {       // stage p = exp(scores) tile
    const int idx = (i << 8) + t;
    const int n = idx >> 4, c = idx & 15;
    float4 val = s4[((n0b + n) << 9) + mc4 + c];
    val.x = __expf(val.x); val.y = __expf(val.y);
    val.z = __expf(val.z); val.w = __expf(val.w);
    pS4[(n << 4) + c] = val;
  }
#pragma unroll
  for (int i = 0; i < 4; ++i) {       // stage V chunk transposed
    const int idx = (i << 8) + t;
    const int dd = idx >> 4, c = idx & 15;   // m0 = 4c, um = (m>>2)&15 = c
    const float4 val = v4[(dd << 9) + mc4 + c];
    const int co = (((dd >> 2) ^ c) << 2) + (dd & 3);
    vtSf[(c << 8) + co] = val.x;            // m = 4c+0
    vtSf[(c << 8) + 64 + co] = val.y;       // m = 4c+1
    vtSf[(c << 8) + 128 + co] = val.z;      // m = 4c+2
    vtSf[(c << 8) + 192 + co] = val.w;      // m = 4c+3
  }
  __syncthreads();

  const int tn = t >> 3, td = t & 7;
  const int n0l = tn << 1, n1l = n0l + 1;
  float4 acc00 = {0,0,0,0}, acc01 = {0,0,0,0};  // n0 x d-blocks {td, td+8}
  float4 acc10 = {0,0,0,0}, acc11 = {0,0,0,0};  // n1

#define PV_STEP(J, AC) {                                       \
    const float4 b0 = vtS4[(m4 << 6) + (J << 4) + c0];         \
    const float4 b1 = vtS4[(m4 << 6) + (J << 4) + (c0 ^ 8)];   \
    acc00.x = fmaf(a0.AC, b0.x, acc00.x);                      \
    acc00.y = fmaf(a0.AC, b0.y, acc00.y);                      \
    acc00.z = fmaf(a0.AC, b0.z, acc00.z);                      \
    acc00.w = fmaf(a0.AC, b0.w, acc00.w);                      \
    acc01.x = fmaf(a0.AC, b1.x, acc01.x);                      \
    acc01.y = fmaf(a0.AC, b1.y, acc01.y);                      \
    acc01.z = fmaf(a0.AC, b1.z, acc01.z);                      \
    acc01.w = fmaf(a0.AC, b1.w, acc01.w);                      \
    acc10.x = fmaf(a1.AC, b0.x, acc10.x);                      \
    acc10.y = fmaf(a1.AC, b0.y, acc10.y);                      \
    acc10.z = fmaf(a1.AC, b0.z, acc10.z);                      \
    acc10.w = fmaf(a1.AC, b0.w, acc10.w);                      \
    acc11.x = fmaf(a1.AC, b1.x, acc11.x);                      \
    acc11.y = fmaf(a1.AC, b1.y, acc11.y);                      \
    acc11.z = fmaf(a1.AC, b1.z, acc11.z);                      \
    acc11.w = fmaf(a1.AC, b1.w, acc11.w);                      \
  }

#pragma unroll
  for (int m4 = 0; m4 < 16; ++m4) {
    const float4 a0 = pS4[(n0l << 4) + m4];
    const float4 a1 = pS4[(n1l << 4) + m4];
    const int c0 = td ^ m4;            // storage col of d-block td at um=m4
    PV_STEP(0, x) PV_STEP(1, y) PV_STEP(2, z) PV_STEP(3, w)
  }
#undef PV_STEP

  // part[ms][n][d], f4 index = (ms<<14) + (n<<4) + dblock : coalesced stores
  float4* part4 = (float4*)part;
  const int pb0 = (ms << 14) + ((n0b + n0l) << 4);
  const int pb1 = (ms << 14) + ((n0b + n1l) << 4);
  part4[pb0 + td] = acc00;
  part4[pb0 + td + 8] = acc01;
  part4[pb1 + td] = acc10;
  part4[pb1 + td + 8] = acc11;
}

// ---------------- K4: reduce partials, divide by l, transpose-store out -------
__global__ __launch_bounds__(256) void k4_reduce(
    const float* __restrict__ part, const float* __restrict__ lpart,
    float* __restrict__ out)
{
  __shared__ float oS[256];
  const int t = threadIdx.x;
  const int nb = blockIdx.x << 2;     // 256 blocks x 4 n
  const int nl = t >> 6, d = t & 63;
  const int n = nb + nl;
  float sum = 0.f;
#pragma unroll
  for (int ms = 0; ms < 32; ++ms)
    sum += part[(ms << 16) + (n << 6) + d];
  const float l = lpart[n] + lpart[1024 + n] + lpart[2048 + n] + lpart[3072 + n];
  oS[(nl << 6) + d] = sum / l;
  __syncthreads();
  const int d2 = t >> 2, n2 = t & 3;
  out[(d2 << 10) + nb + n2] = oS[(n2 << 6) + d2];
}

extern "C" void kernel_launch(void* const* d_in, const int* in_sizes, int n_in,
                              void* d_out, int out_size, void* d_ws, size_t ws_size,
                              hipStream_t stream) {
  const float* query = (const float*)d_in[0];
  const float* key   = (const float*)d_in[1];
  const float* value = (const float*)d_in[2];
  const float* W1    = (const float*)d_in[3];
  const float* b1    = (const float*)d_in[4];
  const float* W2    = (const float*)d_in[5];
  const float* b2    = (const float*)d_in[6];

  float* out    = (float*)d_out;       // (1,64,1024)
  float* scores = out + 65536;         // (1,1024,2048)

  float* ws    = (float*)d_ws;
  float* qp    = ws;                   // 1024*64
  float* kp    = ws + 65536;           // 2048*64
  float* lpart = ws + 196608;          // 4 x 1024 denominator partials
  float* part  = ws + 200704;          // 32 x 1024 x 64 PV partials (n-major)

  k1_proj<<<768, 256, 0, stream>>>(query, key, W1, b1, qp, kp);
  k2_scores<<<512, 256, 0, stream>>>(qp, kp, W2, b2, scores, lpart);
  k3_pv<<<512, 256, 0, stream>>>(scores, value, part);
  k4_reduce<<<256, 256, 0, stream>>>(part, lpart, out);
}

// Round 5
// 99.918 us; speedup vs baseline: 1.4610x; 1.0335x over previous
//
#include <hip/hip_runtime.h>

// Problem constants: d=64, nq=1024, nk=2048, h=64
// ws layout (floats): qp[1024][64] @0, kp[2048][64] @65536,
//   lpart[32][1024] @196608, part[32][1024][64] @229376  (n-major partials)
// scores lives in d_out (out[65536] then scores[1024*2048]); k2 writes it,
// k3 re-reads it and applies exp during LDS staging.

// ---------------- K1: projections ----------------
__global__ __launch_bounds__(256) void k1_proj(
    const float* __restrict__ q, const float* __restrict__ k,
    const float* __restrict__ W1, const float* __restrict__ b1,
    float* __restrict__ qp, float* __restrict__ kp)
{
  __shared__ float tile[256];
  const int t = threadIdx.x;
  const int b = blockIdx.x;
  if (b < 256) {                      // qp: 16 n-tiles x 16 h-tiles
    const int nb = (b & 15) << 6;
    const int hb = (b >> 4) << 2;
    const int n = nb + (t & 63);
    const int h = hb + (t >> 6);      // wave-uniform
    const float* wr = W1 + h * 128;
    float acc = b1[h];
#pragma unroll
    for (int d = 0; d < 64; ++d) acc = fmaf(wr[d], q[(d << 10) + n], acc);
    tile[((t & 63) << 2) + (t >> 6)] = acc;
    __syncthreads();
    qp[((nb + (t >> 2)) << 6) + hb + (t & 3)] = tile[t];
  } else {                            // kp: 32 m-tiles x 16 h-tiles
    const int b2 = b - 256;
    const int mb = (b2 & 31) << 6;
    const int hb = (b2 >> 5) << 2;
    const int m = mb + (t & 63);
    const int h = hb + (t >> 6);
    const float* wr = W1 + h * 128 + 64;
    float acc = 0.f;
#pragma unroll
    for (int d = 0; d < 64; ++d) acc = fmaf(wr[d], k[(d << 11) + m], acc);
    tile[((t & 63) << 2) + (t >> 6)] = acc;
    __syncthreads();
    kp[((mb + (t >> 2)) << 6) + hb + (t & 3)] = tile[t];
  }
}

// ---------------- K2 v2: register-tiled scores ----------------
// Grid 512 = 16 q-tiles(64q) x 32 k-tiles(64k). Block 256 thr = 4 waves
// stacked in q (16q each). Thread tile 4q x 4k (16 accums).
// Lane = (lq:2 | lk:4): q rows = wave*16 + lq*4 + i, k cols = lk*4 + j.
// qS/kS: [row][16 f4], col ^= ((row>>2)&15)  -> fragment reads (rows stride 4)
// hit distinct banks; 8/16-way same-address broadcast across lanes is free.
// Per h4-step: 9 LDS reads feed 192 VALU (add,max,fma) -> VALU-bound.
__global__ __launch_bounds__(256, 2) void k2_scores(
    const float* __restrict__ qp, const float* __restrict__ kp,
    const float* __restrict__ W2, const float* __restrict__ b2p,
    float* __restrict__ scores, float* __restrict__ lpart)
{
  __shared__ float4 qS[1024];         // 64q x 16 f4 (16 KB)
  __shared__ float4 kS[1024];         // 64k x 16 f4 (16 KB)
  __shared__ float4 wS[16];
  const int t = threadIdx.x;
  const int qt = blockIdx.x >> 5;
  const int kt = blockIdx.x & 31;
  const int q0b = qt << 6, k0b = kt << 6;
  const float4* qp4 = (const float4*)qp;
  const float4* kp4 = (const float4*)kp;

#pragma unroll
  for (int i = 0; i < 4; ++i) {       // stage both tiles, coalesced
    const int idx = (i << 8) + t;
    const int row = idx >> 4, c = idx & 15;
    const int cs = c ^ ((row >> 2) & 15);
    qS[(row << 4) + cs] = qp4[((q0b + row) << 4) + c];
    kS[(row << 4) + cs] = kp4[((k0b + row) << 4) + c];
  }
  if (t < 16) wS[t] = ((const float4*)W2)[t];
  __syncthreads();

  const int lane = t & 63, wave = t >> 6;
  const int lq = lane >> 4, lk = lane & 15;
  const int ql0 = (wave << 4) + (lq << 2);   // block-local q row base
  const int kl0 = lk << 2;                   // block-local k col base
  const int sq = (wave << 2) | lq;           // ((ql0>>2)&15)

  float4 acc0 = {0,0,0,0}, acc1 = {0,0,0,0};
  float4 acc2 = {0,0,0,0}, acc3 = {0,0,0,0}; // accI.{x..w} = q-row I, k j=0..3

#pragma unroll 4
  for (int h4 = 0; h4 < 16; ++h4) {
    const float4 wv = wS[h4];
    const int qc = h4 ^ sq, kc = h4 ^ lk;
    const float4 q0f = qS[((ql0 + 0) << 4) + qc];
    const float4 q1f = qS[((ql0 + 1) << 4) + qc];
    const float4 q2f = qS[((ql0 + 2) << 4) + qc];
    const float4 q3f = qS[((ql0 + 3) << 4) + qc];
    const float4 k0f = kS[((kl0 + 0) << 4) + kc];
    const float4 k1f = kS[((kl0 + 1) << 4) + kc];
    const float4 k2f = kS[((kl0 + 2) << 4) + kc];
    const float4 k3f = kS[((kl0 + 3) << 4) + kc];
#define HC(C)                                                        \
    acc0.x = fmaf(wv.C, fmaxf(q0f.C + k0f.C, 0.f), acc0.x);          \
    acc0.y = fmaf(wv.C, fmaxf(q0f.C + k1f.C, 0.f), acc0.y);          \
    acc0.z = fmaf(wv.C, fmaxf(q0f.C + k2f.C, 0.f), acc0.z);          \
    acc0.w = fmaf(wv.C, fmaxf(q0f.C + k3f.C, 0.f), acc0.w);          \
    acc1.x = fmaf(wv.C, fmaxf(q1f.C + k0f.C, 0.f), acc1.x);          \
    acc1.y = fmaf(wv.C, fmaxf(q1f.C + k1f.C, 0.f), acc1.y);          \
    acc1.z = fmaf(wv.C, fmaxf(q1f.C + k2f.C, 0.f), acc1.z);          \
    acc1.w = fmaf(wv.C, fmaxf(q1f.C + k3f.C, 0.f), acc1.w);          \
    acc2.x = fmaf(wv.C, fmaxf(q2f.C + k0f.C, 0.f), acc2.x);          \
    acc2.y = fmaf(wv.C, fmaxf(q2f.C + k1f.C, 0.f), acc2.y);          \
    acc2.z = fmaf(wv.C, fmaxf(q2f.C + k2f.C, 0.f), acc2.z);          \
    acc2.w = fmaf(wv.C, fmaxf(q2f.C + k3f.C, 0.f), acc2.w);          \
    acc3.x = fmaf(wv.C, fmaxf(q3f.C + k0f.C, 0.f), acc3.x);          \
    acc3.y = fmaf(wv.C, fmaxf(q3f.C + k1f.C, 0.f), acc3.y);          \
    acc3.z = fmaf(wv.C, fmaxf(q3f.C + k2f.C, 0.f), acc3.z);          \
    acc3.w = fmaf(wv.C, fmaxf(q3f.C + k3f.C, 0.f), acc3.w);
    HC(x) HC(y) HC(z) HC(w)
#undef HC
  }

  const float b2v = b2p[0];
  float4* sc4 = (float4*)scores;
  const int kcol = (k0b >> 2) + lk;
#define ROW_OUT(I, ACC) {                                            \
    float4 s = ACC;                                                  \
    s.x += b2v; s.y += b2v; s.z += b2v; s.w += b2v;                  \
    sc4[((q0b + ql0 + I) << 9) + kcol] = s;                          \
    float e = __expf(s.x) + __expf(s.y) + __expf(s.z) + __expf(s.w); \
    e += __shfl_xor(e, 1); e += __shfl_xor(e, 2);                    \
    e += __shfl_xor(e, 4); e += __shfl_xor(e, 8);                    \
    if (lk == 0) lpart[(kt << 10) + q0b + ql0 + I] = e; }
  ROW_OUT(0, acc0) ROW_OUT(1, acc1) ROW_OUT(2, acc2) ROW_OUT(3, acc3)
#undef ROW_OUT
}

// ---------------- K3: partial PV. part[ms][n][d] = sum_{m in split} p*V ------
__global__ __launch_bounds__(256, 2) void k3_pv(
    const float* __restrict__ scores, const float* __restrict__ v,
    float* __restrict__ part)
{
  __shared__ float4 pS4[1024];        // 64n x 16f4 row-major (exp(scores))
  __shared__ float4 vtS4[1024];       // 64m x 16f4 transposed V, swizzled
  float* vtSf = (float*)vtS4;
  const int t = threadIdx.x;
  const int nt = blockIdx.x >> 5;
  const int ms = blockIdx.x & 31;
  const int n0b = nt << 6;
  const int mc4 = ms << 4;

  const float4* s4 = (const float4*)scores;
  const float4* v4 = (const float4*)v;
#pragma unroll
  for (int i = 0; i < 4; ++i) {       // stage p = exp(scores) tile
    const int idx = (i << 8) + t;
    const int n = idx >> 4, c = idx & 15;
    float4 val = s4[((n0b + n) << 9) + mc4 + c];
    val.x = __expf(val.x); val.y = __expf(val.y);
    val.z = __expf(val.z); val.w = __expf(val.w);
    pS4[(n << 4) + c] = val;
  }
#pragma unroll
  for (int i = 0; i < 4; ++i) {       // stage V chunk transposed
    const int idx = (i << 8) + t;
    const int dd = idx >> 4, c = idx & 15;
    const float4 val = v4[(dd << 9) + mc4 + c];
    const int co = (((dd >> 2) ^ c) << 2) + (dd & 3);
    vtSf[(c << 8) + co] = val.x;
    vtSf[(c << 8) + 64 + co] = val.y;
    vtSf[(c << 8) + 128 + co] = val.z;
    vtSf[(c << 8) + 192 + co] = val.w;
  }
  __syncthreads();

  const int tn = t >> 3, td = t & 7;
  const int n0l = tn << 1, n1l = n0l + 1;
  float4 acc00 = {0,0,0,0}, acc01 = {0,0,0,0};
  float4 acc10 = {0,0,0,0}, acc11 = {0,0,0,0};

#define PV_STEP(J, AC) {                                       \
    const float4 b0 = vtS4[(m4 << 6) + (J << 4) + c0];         \
    const float4 b1 = vtS4[(m4 << 6) + (J << 4) + (c0 ^ 8)];   \
    acc00.x = fmaf(a0.AC, b0.x, acc00.x);                      \
    acc00.y = fmaf(a0.AC, b0.y, acc00.y);                      \
    acc00.z = fmaf(a0.AC, b0.z, acc00.z);                      \
    acc00.w = fmaf(a0.AC, b0.w, acc00.w);                      \
    acc01.x = fmaf(a0.AC, b1.x, acc01.x);                      \
    acc01.y = fmaf(a0.AC, b1.y, acc01.y);                      \
    acc01.z = fmaf(a0.AC, b1.z, acc01.z);                      \
    acc01.w = fmaf(a0.AC, b1.w, acc01.w);                      \
    acc10.x = fmaf(a1.AC, b0.x, acc10.x);                      \
    acc10.y = fmaf(a1.AC, b0.y, acc10.y);                      \
    acc10.z = fmaf(a1.AC, b0.z, acc10.z);                      \
    acc10.w = fmaf(a1.AC, b0.w, acc10.w);                      \
    acc11.x = fmaf(a1.AC, b1.x, acc11.x);                      \
    acc11.y = fmaf(a1.AC, b1.y, acc11.y);                      \
    acc11.z = fmaf(a1.AC, b1.z, acc11.z);                      \
    acc11.w = fmaf(a1.AC, b1.w, acc11.w);                      \
  }

#pragma unroll
  for (int m4 = 0; m4 < 16; ++m4) {
    const float4 a0 = pS4[(n0l << 4) + m4];
    const float4 a1 = pS4[(n1l << 4) + m4];
    const int c0 = td ^ m4;
    PV_STEP(0, x) PV_STEP(1, y) PV_STEP(2, z) PV_STEP(3, w)
  }
#undef PV_STEP

  float4* part4 = (float4*)part;
  const int pb0 = (ms << 14) + ((n0b + n0l) << 4);
  const int pb1 = (ms << 14) + ((n0b + n1l) << 4);
  part4[pb0 + td] = acc00;
  part4[pb0 + td + 8] = acc01;
  part4[pb1 + td] = acc10;
  part4[pb1 + td + 8] = acc11;
}

// ---------------- K4: reduce partials, divide by l, transpose-store out -------
__global__ __launch_bounds__(256) void k4_reduce(
    const float* __restrict__ part, const float* __restrict__ lpart,
    float* __restrict__ out)
{
  __shared__ float oS[256];
  const int t = threadIdx.x;
  const int nb = blockIdx.x << 2;     // 256 blocks x 4 n
  const int nl = t >> 6, d = t & 63;
  const int n = nb + nl;
  float sum = 0.f;
#pragma unroll
  for (int ms = 0; ms < 32; ++ms)
    sum += part[(ms << 16) + (n << 6) + d];
  float l = 0.f;
#pragma unroll
  for (int kt = 0; kt < 32; ++kt)
    l += lpart[(kt << 10) + n];
  oS[(nl << 6) + d] = sum / l;
  __syncthreads();
  const int d2 = t >> 2, n2 = t & 3;
  out[(d2 << 10) + nb + n2] = oS[(n2 << 6) + d2];
}

extern "C" void kernel_launch(void* const* d_in, const int* in_sizes, int n_in,
                              void* d_out, int out_size, void* d_ws, size_t ws_size,
                              hipStream_t stream) {
  const float* query = (const float*)d_in[0];
  const float* key   = (const float*)d_in[1];
  const float* value = (const float*)d_in[2];
  const float* W1    = (const float*)d_in[3];
  const float* b1    = (const float*)d_in[4];
  const float* W2    = (const float*)d_in[5];
  const float* b2    = (const float*)d_in[6];

  float* out    = (float*)d_out;       // (1,64,1024)
  float* scores = out + 65536;         // (1,1024,2048)

  float* ws    = (float*)d_ws;
  float* qp    = ws;                   // 1024*64
  float* kp    = ws + 65536;           // 2048*64
  float* lpart = ws + 196608;          // 32 x 1024 denominator partials
  float* part  = ws + 229376;          // 32 x 1024 x 64 PV partials (n-major)

  k1_proj<<<768, 256, 0, stream>>>(query, key, W1, b1, qp, kp);
  k2_scores<<<512, 256, 0, stream>>>(qp, kp, W2, b2, scores, lpart);
  k3_pv<<<512, 256, 0, stream>>>(scores, value, part);
  k4_reduce<<<256, 256, 0, stream>>>(part, lpart, out);
}